// Round 2
// baseline (220.366 us; speedup 1.0000x reference)
//
#include <hip/hip_runtime.h>

#define HH 2048
#define NPIX (HH * HH)      // 4194304
#define NBINS 256
#define NQ (NPIX / 4)       // 1048576 float4 quads

// workspace layout:
//   [0, 6*256) u32   : histograms (src c0,c1,c2, tar c0,c1,c2)
//   then 3*256 float : LUT (matched values as float)
//   then 1 double    : global sum
#define HIST_BYTES (6 * NBINS * 4)
#define TABLE_BYTES (3 * NBINS * 4)

__device__ __forceinline__ float denorm255(float x) {
    // matches clip((x+1)*0.5, 0, 1) * 255 in fp32
    return fminf(fmaxf((x + 1.0f) * 0.5f, 0.0f), 1.0f) * 255.0f;
}

__global__ void hist_kernel(const float* __restrict__ in, const float* __restrict__ tar,
                            const float* __restrict__ ms, const float* __restrict__ mt,
                            unsigned* __restrict__ ghist) {
    __shared__ unsigned lh[6 * NBINS];
    for (int i = threadIdx.x; i < 6 * NBINS; i += blockDim.x) lh[i] = 0;
    __syncthreads();

    const float BSCALE = 256.0f / 255.0f;  // same fp32 constant as jnp's multiply
    const int stride = gridDim.x * blockDim.x;
    for (int idx = blockIdx.x * blockDim.x + threadIdx.x; idx < NQ; idx += stride) {
        float4 m4 = ((const float4*)ms)[idx];
        float4 t4 = ((const float4*)mt)[idx];
        float mv[4] = {m4.x, m4.y, m4.z, m4.w};
        float tv[4] = {t4.x, t4.y, t4.z, t4.w};
        #pragma unroll
        for (int ch = 0; ch < 3; ++ch) {
            float4 a = ((const float4*)(in + (size_t)ch * NPIX))[idx];
            float4 b = ((const float4*)(tar + (size_t)ch * NPIX))[idx];
            float av[4] = {a.x, a.y, a.z, a.w};
            float bv[4] = {b.x, b.y, b.z, b.w};
            #pragma unroll
            for (int k = 0; k < 4; ++k) {
                if (mv[k] != 0.0f) {
                    float v = denorm255(av[k]);
                    int bin = min(max((int)floorf(v * BSCALE), 0), NBINS - 1);
                    atomicAdd(&lh[ch * NBINS + bin], 1u);
                }
                if (tv[k] != 0.0f) {
                    float v = denorm255(bv[k]);
                    int bin = min(max((int)floorf(v * BSCALE), 0), NBINS - 1);
                    atomicAdd(&lh[(3 + ch) * NBINS + bin], 1u);
                }
            }
        }
    }
    __syncthreads();
    for (int i = threadIdx.x; i < 6 * NBINS; i += blockDim.x)
        if (lh[i]) atomicAdd(&ghist[i], lh[i]);
}

__global__ void table_kernel(const unsigned* __restrict__ ghist, float* __restrict__ gtable) {
    __shared__ float cdf[6][NBINS];
    __shared__ float tot[6];
    const int t = threadIdx.x;  // 0..255
    #pragma unroll
    for (int j = 0; j < 6; ++j) cdf[j][t] = (float)ghist[j * NBINS + t];
    __syncthreads();
    if (t < 6) {
        // integer-valued f32 sums < 2^24: exact, matches jnp.cumsum bitwise
        float s = 0.0f;
        for (int i = 0; i < NBINS; ++i) { s += cdf[t][i]; cdf[t][i] = s; }
        tot[t] = fmaxf(cdf[t][NBINS - 1], 1.0f);
    }
    __syncthreads();
    #pragma unroll
    for (int j = 0; j < 6; ++j) cdf[j][t] = cdf[j][t] / tot[j];
    __syncthreads();

    #pragma unroll
    for (int ch = 0; ch < 3; ++ch) {
        const float d = cdf[ch][t];
        const float* ref = cdf[3 + ch];
        // searchsorted side='left': first idx with ref[idx] >= d
        int lo = 0, hi = NBINS;
        while (lo < hi) {
            int mid = (lo + hi) >> 1;
            if (ref[mid] < d) lo = mid + 1; else hi = mid;
        }
        int cand = min(max(lo, 1), NBINS - 1);
        int tab = (ref[cand - 1] <= d && ref[cand] >= d) ? cand : t;
        if (t == 0) tab = 0;
        if (t == NBINS - 1) tab = NBINS - 1;
        gtable[ch * NBINS + t] = (float)tab;
    }
}

__global__ void loss_kernel(const float* __restrict__ in, const float* __restrict__ ms,
                            const float* __restrict__ gtable, double* __restrict__ gsum) {
    __shared__ float lt[3 * NBINS];
    for (int i = threadIdx.x; i < 3 * NBINS; i += blockDim.x) lt[i] = gtable[i];
    __syncthreads();

    float acc = 0.0f;
    const int stride = gridDim.x * blockDim.x;
    for (int idx = blockIdx.x * blockDim.x + threadIdx.x; idx < NQ; idx += stride) {
        float4 m4 = ((const float4*)ms)[idx];
        float mv[4] = {m4.x, m4.y, m4.z, m4.w};
        #pragma unroll
        for (int ch = 0; ch < 3; ++ch) {
            float4 a = ((const float4*)(in + (size_t)ch * NPIX))[idx];
            float av[4] = {a.x, a.y, a.z, a.w};
            #pragma unroll
            for (int k = 0; k < 4; ++k) {
                if (mv[k] != 0.0f) {
                    float v = denorm255(av[k]);
                    int pix = min(max((int)v, 0), NBINS - 1);  // trunc like astype(int32)
                    acc += fabsf(v - lt[ch * NBINS + pix]);
                }
                // unmasked pixels: input_match == input_masked -> contributes 0
            }
        }
    }

    // wave64 tree reduce, then one double atomic per block
    #pragma unroll
    for (int off = 32; off; off >>= 1) acc += __shfl_down(acc, off, 64);
    __shared__ float wsum[4];
    const int wid = threadIdx.x >> 6;
    if ((threadIdx.x & 63) == 0) wsum[wid] = acc;
    __syncthreads();
    if (threadIdx.x == 0) {
        float b = wsum[0] + wsum[1] + wsum[2] + wsum[3];
        atomicAdd(gsum, (double)b);
    }
}

__global__ void finalize_kernel(const double* __restrict__ gsum, float* __restrict__ out) {
    out[0] = (float)(gsum[0] / (double)(3 * NPIX));
}

extern "C" void kernel_launch(void* const* d_in, const int* in_sizes, int n_in,
                              void* d_out, int out_size, void* d_ws, size_t ws_size,
                              hipStream_t stream) {
    const float* in  = (const float*)d_in[0];
    const float* tar = (const float*)d_in[1];
    const float* ms  = (const float*)d_in[2];
    const float* mt  = (const float*)d_in[3];
    float* out = (float*)d_out;

    unsigned* ghist = (unsigned*)d_ws;
    float* gtable   = (float*)((char*)d_ws + HIST_BYTES);
    double* gsum    = (double*)((char*)d_ws + HIST_BYTES + TABLE_BYTES);

    hipMemsetAsync(d_ws, 0, HIST_BYTES + TABLE_BYTES + 8, stream);

    hist_kernel<<<2048, 256, 0, stream>>>(in, tar, ms, mt, ghist);
    table_kernel<<<1, NBINS, 0, stream>>>(ghist, gtable);
    loss_kernel<<<2048, 256, 0, stream>>>(in, ms, gtable, gsum);
    finalize_kernel<<<1, 1, 0, stream>>>(gsum, out);
}

// Round 3
// 167.983 us; speedup vs baseline: 1.3118x; 1.3118x over previous
//
#include <hip/hip_runtime.h>

#define HH 2048
#define NPIX (HH * HH)      // 4194304
#define NBINS 256
#define NQ (NPIX / 4)       // 1048576 float4 quads

// workspace layout (zeroed by memset each launch):
//   u32 ghist[6][256] : masked hist counts (src c0..c2, tar c0..c2)
//   u32 gcnt [3][256] : per-trunc-bin masked pixel counts (src)
//   f32 gfrac[3][256] : per-trunc-bin frac sums (src)
#define GHIST_WORDS (6 * NBINS)
#define GCNT_WORDS  (3 * NBINS)
#define GFRAC_WORDS (3 * NBINS)
#define WS_ZERO_BYTES ((GHIST_WORDS + GCNT_WORDS + GFRAC_WORDS) * 4)

__device__ __forceinline__ float denorm255(float x) {
    // matches clip((x+1)*0.5, 0, 1) * 255 in fp32 (no fma contraction possible)
    return fminf(fmaxf((x + 1.0f) * 0.5f, 0.0f), 1.0f) * 255.0f;
}

__global__ __launch_bounds__(512) void fused_hist(
        const float* __restrict__ in, const float* __restrict__ tar,
        const float* __restrict__ ms, const float* __restrict__ mt,
        unsigned* __restrict__ ghist, unsigned* __restrict__ gcnt,
        float* __restrict__ gfrac) {
    __shared__ unsigned lhs[3 * NBINS];  // src hist
    __shared__ unsigned lht[3 * NBINS];  // tar hist
    __shared__ unsigned lc [3 * NBINS];  // src trunc-bin counts
    __shared__ float    lf [3 * NBINS];  // src trunc-bin frac sums
    for (int i = threadIdx.x; i < 3 * NBINS; i += blockDim.x) {
        lhs[i] = 0u; lht[i] = 0u; lc[i] = 0u; lf[i] = 0.0f;
    }
    __syncthreads();

    const float BSCALE = 256.0f / 255.0f;  // same nearest-f32 constant as jnp
    const int stride = gridDim.x * blockDim.x;
    for (int idx = blockIdx.x * blockDim.x + threadIdx.x; idx < NQ; idx += stride) {
        float4 m4 = ((const float4*)ms)[idx];
        float4 t4 = ((const float4*)mt)[idx];
        float mv[4] = {m4.x, m4.y, m4.z, m4.w};
        float tv[4] = {t4.x, t4.y, t4.z, t4.w};
        #pragma unroll
        for (int ch = 0; ch < 3; ++ch) {
            float4 a = ((const float4*)(in  + (size_t)ch * NPIX))[idx];
            float4 b = ((const float4*)(tar + (size_t)ch * NPIX))[idx];
            float av[4] = {a.x, a.y, a.z, a.w};
            float bv[4] = {b.x, b.y, b.z, b.w};
            #pragma unroll
            for (int k = 0; k < 4; ++k) {
                if (mv[k] != 0.0f) {
                    float v = denorm255(av[k]);
                    int hb = min(max((int)floorf(v * BSCALE), 0), NBINS - 1);
                    atomicAdd(&lhs[ch * NBINS + hb], 1u);
                    int tb = min((int)v, NBINS - 1);      // trunc; v>=0
                    atomicAdd(&lc[ch * NBINS + tb], 1u);
                    // v - tb is exact in fp32 (tb <= v < tb+1)
                    atomicAdd(&lf[ch * NBINS + tb], v - (float)tb);
                }
                if (tv[k] != 0.0f) {
                    float v = denorm255(bv[k]);
                    int hb = min(max((int)floorf(v * BSCALE), 0), NBINS - 1);
                    atomicAdd(&lht[ch * NBINS + hb], 1u);
                }
            }
        }
    }
    __syncthreads();
    for (int i = threadIdx.x; i < 3 * NBINS; i += blockDim.x) {
        unsigned a = lhs[i]; if (a) atomicAdd(&ghist[i], a);
        unsigned b = lht[i]; if (b) atomicAdd(&ghist[3 * NBINS + i], b);
        unsigned c = lc[i];  if (c) atomicAdd(&gcnt[i], c);
        float    f = lf[i];  if (f != 0.0f) atomicAdd(&gfrac[i], f);
    }
}

__global__ __launch_bounds__(NBINS) void table_loss(
        const unsigned* __restrict__ ghist, const unsigned* __restrict__ gcnt,
        const float* __restrict__ gfrac, float* __restrict__ out) {
    __shared__ float cdf[6][NBINS];
    __shared__ float tot[6];
    const int t = threadIdx.x;  // 0..255
    #pragma unroll
    for (int j = 0; j < 6; ++j) cdf[j][t] = (float)ghist[j * NBINS + t];
    __syncthreads();
    // Hillis-Steele inclusive scan; all partials are integers < 2^24 -> exact
    #pragma unroll
    for (int off = 1; off < NBINS; off <<= 1) {
        float add[6];
        #pragma unroll
        for (int j = 0; j < 6; ++j) add[j] = (t >= off) ? cdf[j][t - off] : 0.0f;
        __syncthreads();
        #pragma unroll
        for (int j = 0; j < 6; ++j) cdf[j][t] += add[j];
        __syncthreads();
    }
    if (t < 6) tot[t] = fmaxf(cdf[t][NBINS - 1], 1.0f);
    __syncthreads();
    #pragma unroll
    for (int j = 0; j < 6; ++j) cdf[j][t] = cdf[j][t] / tot[j];
    __syncthreads();

    double lsum = 0.0;
    #pragma unroll
    for (int ch = 0; ch < 3; ++ch) {
        const float d = cdf[ch][t];
        const float* ref = cdf[3 + ch];
        // searchsorted side='left': first idx with ref[idx] >= d
        int lo = 0, hi = NBINS;
        while (lo < hi) {
            int mid = (lo + hi) >> 1;
            if (ref[mid] < d) lo = mid + 1; else hi = mid;
        }
        int cand = min(max(lo, 1), NBINS - 1);
        int T = (ref[cand - 1] <= d && ref[cand] >= d) ? cand : t;
        if (t == 0) T = 0;
        if (t == NBINS - 1) T = NBINS - 1;

        const int b = t;
        const double c = (double)gcnt[ch * NBINS + t];
        const double F = (double)gfrac[ch * NBINS + t];
        // masked pixels with trunc(v)=b: |v - T| = (b-T)+f if T<=b else (T-b)-f
        lsum += (T <= b) ? (c * (double)(b - T) + F)
                         : (c * (double)(T - b) - F);
    }
    // reduce doubles across 4 waves
    #pragma unroll
    for (int off = 32; off; off >>= 1) lsum += __shfl_down(lsum, off, 64);
    __shared__ double wsum[4];
    if ((t & 63) == 0) wsum[t >> 6] = lsum;
    __syncthreads();
    if (t == 0)
        out[0] = (float)((wsum[0] + wsum[1] + wsum[2] + wsum[3]) / (double)(3 * NPIX));
}

extern "C" void kernel_launch(void* const* d_in, const int* in_sizes, int n_in,
                              void* d_out, int out_size, void* d_ws, size_t ws_size,
                              hipStream_t stream) {
    const float* in  = (const float*)d_in[0];
    const float* tar = (const float*)d_in[1];
    const float* ms  = (const float*)d_in[2];
    const float* mt  = (const float*)d_in[3];
    float* out = (float*)d_out;

    unsigned* ghist = (unsigned*)d_ws;
    unsigned* gcnt  = ghist + GHIST_WORDS;
    float*    gfrac = (float*)(gcnt + GCNT_WORDS);

    hipMemsetAsync(d_ws, 0, WS_ZERO_BYTES, stream);
    fused_hist<<<512, 512, 0, stream>>>(in, tar, ms, mt, ghist, gcnt, gfrac);
    table_loss<<<1, NBINS, 0, stream>>>(ghist, gcnt, gfrac, out);
}

// Round 4
// 166.425 us; speedup vs baseline: 1.3241x; 1.0094x over previous
//
#include <hip/hip_runtime.h>

#define HH 2048
#define NPIX (HH * HH)      // 4194304
#define NBINS 256
#define NQ (NPIX / 4)       // 1048576 float4 quads

// workspace layout (zeroed by memset each launch):
//   u32 ghist[6][256] : masked hist counts (src c0..c2, tar c0..c2)  = 6144 B
//   u64 gpk  [3][256] : packed (count<<42 | sum of floor(frac*2^22)) = 6144 B
#define GHIST_WORDS (6 * NBINS)
#define GPK_WORDS   (3 * NBINS)
#define WS_ZERO_BYTES (GHIST_WORDS * 4 + GPK_WORDS * 8)

#define FRAC_BITS 22
#define CNT_SHIFT 42
#define FRAC_MASK ((1ULL << CNT_SHIFT) - 1)

__device__ __forceinline__ float denorm255(float x) {
    // matches clip((x+1)*0.5, 0, 1) * 255 in fp32
    return fminf(fmaxf((x + 1.0f) * 0.5f, 0.0f), 1.0f) * 255.0f;
}

__global__ __launch_bounds__(512, 8) void fused_hist(
        const float* __restrict__ in, const float* __restrict__ tar,
        const float* __restrict__ ms, const float* __restrict__ mt,
        unsigned* __restrict__ ghist, unsigned long long* __restrict__ gpk) {
    __shared__ unsigned lhs[3 * NBINS];            // src hist
    __shared__ unsigned lht[3 * NBINS];            // tar hist
    __shared__ unsigned long long lpk[3 * NBINS];  // src (cnt<<42 | frac fixpt)
    for (int i = threadIdx.x; i < 3 * NBINS; i += blockDim.x) {
        lhs[i] = 0u; lht[i] = 0u; lpk[i] = 0ull;
    }
    __syncthreads();

    const float BSCALE = 256.0f / 255.0f;   // same nearest-f32 constant as jnp
    const float FSCALE = 4194304.0f;        // 2^22 (exact power-of-two scale)
    const int stride = gridDim.x * blockDim.x;
    for (int idx = blockIdx.x * blockDim.x + threadIdx.x; idx < NQ; idx += stride) {
        float4 m4 = ((const float4*)ms)[idx];
        float4 t4 = ((const float4*)mt)[idx];
        float mv[4] = {m4.x, m4.y, m4.z, m4.w};
        float tv[4] = {t4.x, t4.y, t4.z, t4.w};
        #pragma unroll
        for (int ch = 0; ch < 3; ++ch) {
            float4 a = ((const float4*)(in  + (size_t)ch * NPIX))[idx];
            float4 b = ((const float4*)(tar + (size_t)ch * NPIX))[idx];
            float av[4] = {a.x, a.y, a.z, a.w};
            float bv[4] = {b.x, b.y, b.z, b.w};
            #pragma unroll
            for (int k = 0; k < 4; ++k) {
                if (mv[k] != 0.0f) {
                    float v = denorm255(av[k]);
                    int hb = min(max((int)floorf(v * BSCALE), 0), NBINS - 1);
                    atomicAdd(&lhs[ch * NBINS + hb], 1u);
                    int tb = min((int)v, NBINS - 1);          // trunc; v >= 0
                    // f = v - tb is exact fp32; f*2^22 exact; trunc error < 2^-22
                    unsigned fr = (unsigned)((v - (float)tb) * FSCALE);
                    atomicAdd(&lpk[ch * NBINS + tb],
                              (1ULL << CNT_SHIFT) | (unsigned long long)fr);
                }
                if (tv[k] != 0.0f) {
                    float v = denorm255(bv[k]);
                    int hb = min(max((int)floorf(v * BSCALE), 0), NBINS - 1);
                    atomicAdd(&lht[ch * NBINS + hb], 1u);
                }
            }
        }
    }
    __syncthreads();
    for (int i = threadIdx.x; i < 3 * NBINS; i += blockDim.x) {
        unsigned a = lhs[i]; if (a) atomicAdd(&ghist[i], a);
        unsigned b = lht[i]; if (b) atomicAdd(&ghist[3 * NBINS + i], b);
        unsigned long long p = lpk[i]; if (p) atomicAdd(&gpk[i], p);
    }
}

__global__ __launch_bounds__(NBINS) void table_loss(
        const unsigned* __restrict__ ghist,
        const unsigned long long* __restrict__ gpk,
        float* __restrict__ out) {
    __shared__ float cdf[6][NBINS];
    __shared__ float tot[6];
    const int t = threadIdx.x;  // 0..255
    #pragma unroll
    for (int j = 0; j < 6; ++j) cdf[j][t] = (float)ghist[j * NBINS + t];
    __syncthreads();
    // Hillis-Steele inclusive scan; all partials are integers < 2^24 -> exact
    #pragma unroll
    for (int off = 1; off < NBINS; off <<= 1) {
        float add[6];
        #pragma unroll
        for (int j = 0; j < 6; ++j) add[j] = (t >= off) ? cdf[j][t - off] : 0.0f;
        __syncthreads();
        #pragma unroll
        for (int j = 0; j < 6; ++j) cdf[j][t] += add[j];
        __syncthreads();
    }
    if (t < 6) tot[t] = fmaxf(cdf[t][NBINS - 1], 1.0f);
    __syncthreads();
    #pragma unroll
    for (int j = 0; j < 6; ++j) cdf[j][t] = cdf[j][t] / tot[j];
    __syncthreads();

    double lsum = 0.0;
    #pragma unroll
    for (int ch = 0; ch < 3; ++ch) {
        const float d = cdf[ch][t];
        const float* ref = cdf[3 + ch];
        // searchsorted side='left': first idx with ref[idx] >= d
        int lo = 0, hi = NBINS;
        while (lo < hi) {
            int mid = (lo + hi) >> 1;
            if (ref[mid] < d) lo = mid + 1; else hi = mid;
        }
        int cand = min(max(lo, 1), NBINS - 1);
        int T = (ref[cand - 1] <= d && ref[cand] >= d) ? cand : t;
        if (t == 0) T = 0;
        if (t == NBINS - 1) T = NBINS - 1;

        const int b = t;
        const unsigned long long pk = gpk[ch * NBINS + t];
        const double c = (double)(pk >> CNT_SHIFT);
        const double F = (double)(pk & FRAC_MASK) * (1.0 / 4194304.0);
        // masked pixels with trunc(v)=b: |v - T| = (b-T)+f if T<=b else (T-b)-f
        lsum += (T <= b) ? (c * (double)(b - T) + F)
                         : (c * (double)(T - b) - F);
    }
    // reduce doubles across 4 waves
    #pragma unroll
    for (int off = 32; off; off >>= 1) lsum += __shfl_down(lsum, off, 64);
    __shared__ double wsum[4];
    if ((t & 63) == 0) wsum[t >> 6] = lsum;
    __syncthreads();
    if (t == 0)
        out[0] = (float)((wsum[0] + wsum[1] + wsum[2] + wsum[3]) / (double)(3 * NPIX));
}

extern "C" void kernel_launch(void* const* d_in, const int* in_sizes, int n_in,
                              void* d_out, int out_size, void* d_ws, size_t ws_size,
                              hipStream_t stream) {
    const float* in  = (const float*)d_in[0];
    const float* tar = (const float*)d_in[1];
    const float* ms  = (const float*)d_in[2];
    const float* mt  = (const float*)d_in[3];
    float* out = (float*)d_out;

    unsigned* ghist = (unsigned*)d_ws;
    unsigned long long* gpk = (unsigned long long*)((char*)d_ws + GHIST_WORDS * 4);

    hipMemsetAsync(d_ws, 0, WS_ZERO_BYTES, stream);
    fused_hist<<<1024, 512, 0, stream>>>(in, tar, ms, mt, ghist, gpk);
    table_loss<<<1, NBINS, 0, stream>>>(ghist, gpk, out);
}

// Round 5
// 160.729 us; speedup vs baseline: 1.3710x; 1.0354x over previous
//
#include <hip/hip_runtime.h>

#define HH 2048
#define NPIX (HH * HH)      // 4194304
#define NBINS 256
#define NRBINS 512          // refined bins: r = hb + tb, r in [0,510]
#define NQ (NPIX / 4)       // 1048576 float4 quads

#define BLOCKS 512
#define THREADS 512
#define ITERS (NQ / (BLOCKS * THREADS))   // 4 exactly

#define CNT_SHIFT 42
#define FRAC_MASK ((1ULL << CNT_SHIFT) - 1)

// workspace (zeroed each launch):
//   u64 gpk[3][512] : refined src stats (count<<42 | sum floor(frac*2^22))
//   u32 ght[3][256] : tar masked hist
#define GPK_WORDS (3 * NRBINS)
#define GHT_WORDS (3 * NBINS)
#define WS_ZERO_BYTES (GPK_WORDS * 8 + GHT_WORDS * 4)

__device__ __forceinline__ float denorm255(float x) {
    // matches clip((x+1)*0.5, 0, 1) * 255 in fp32
    return fminf(fmaxf((x + 1.0f) * 0.5f, 0.0f), 1.0f) * 255.0f;
}

__global__ __launch_bounds__(THREADS, 2) void fused_hist(
        const float* __restrict__ in, const float* __restrict__ tar,
        const float* __restrict__ ms, const float* __restrict__ mt,
        unsigned long long* __restrict__ gpk, unsigned* __restrict__ ght) {
    __shared__ unsigned long long lpk[3 * NRBINS];  // 12 KB
    __shared__ unsigned lht[3 * NBINS];             // 3 KB
    for (int i = threadIdx.x; i < 3 * NRBINS; i += THREADS) lpk[i] = 0ULL;
    for (int i = threadIdx.x; i < 3 * NBINS; i += THREADS) lht[i] = 0u;
    __syncthreads();

    const float BSCALE = 256.0f / 255.0f;  // same nearest-f32 constant as jnp
    const float FSCALE = 4194304.0f;       // 2^22
    const int stride = BLOCKS * THREADS;
    int idx = blockIdx.x * THREADS + threadIdx.x;

    // software pipeline: load iteration s+1 while binning iteration s
    float4 cm  = ((const float4*)ms)[idx];
    float4 ct  = ((const float4*)mt)[idx];
    float4 ca0 = ((const float4*)(in))[idx];
    float4 ca1 = ((const float4*)(in + NPIX))[idx];
    float4 ca2 = ((const float4*)(in + 2 * NPIX))[idx];
    float4 cb0 = ((const float4*)(tar))[idx];
    float4 cb1 = ((const float4*)(tar + NPIX))[idx];
    float4 cb2 = ((const float4*)(tar + 2 * NPIX))[idx];

    #pragma unroll
    for (int s = 0; s < ITERS; ++s) {
        float4 nm, nt4, na0, na1, na2, nb0, nb1, nb2;
        const int nidx = idx + stride;
        if (s < ITERS - 1) {
            nm  = ((const float4*)ms)[nidx];
            nt4 = ((const float4*)mt)[nidx];
            na0 = ((const float4*)(in))[nidx];
            na1 = ((const float4*)(in + NPIX))[nidx];
            na2 = ((const float4*)(in + 2 * NPIX))[nidx];
            nb0 = ((const float4*)(tar))[nidx];
            nb1 = ((const float4*)(tar + NPIX))[nidx];
            nb2 = ((const float4*)(tar + 2 * NPIX))[nidx];
        }

        const float mv[4] = {cm.x, cm.y, cm.z, cm.w};
        const float tv[4] = {ct.x, ct.y, ct.z, ct.w};
        const float av[3][4] = {{ca0.x, ca0.y, ca0.z, ca0.w},
                                {ca1.x, ca1.y, ca1.z, ca1.w},
                                {ca2.x, ca2.y, ca2.z, ca2.w}};
        const float bv[3][4] = {{cb0.x, cb0.y, cb0.z, cb0.w},
                                {cb1.x, cb1.y, cb1.z, cb1.w},
                                {cb2.x, cb2.y, cb2.z, cb2.w}};

        #pragma unroll
        for (int ch = 0; ch < 3; ++ch) {
            #pragma unroll
            for (int k = 0; k < 4; ++k) {
                // --- src pixel: one u64 atomic carries hist count + trunc-bin frac
                float v = denorm255(av[ch][k]);
                int hb = min((int)(v * BSCALE), NBINS - 1);  // trunc==floor, v>=0
                int tb = (int)v;                             // in [0,255]
                // v - tb is Sterbenz-exact; *2^22 exact scale; trunc err < 2^-22
                unsigned fr = (unsigned)((v - (float)tb) * FSCALE);
                unsigned long long pk =
                    (1ULL << CNT_SHIFT) | (unsigned long long)fr;
                pk = (mv[k] != 0.0f) ? pk : 0ULL;  // branchless predication
                atomicAdd(&lpk[ch * NRBINS + hb + tb], pk);

                // --- tar pixel: hist count only
                float w = denorm255(bv[ch][k]);
                int wb = min((int)(w * BSCALE), NBINS - 1);
                atomicAdd(&lht[ch * NBINS + wb], (tv[k] != 0.0f) ? 1u : 0u);
            }
        }
        if (s < ITERS - 1) {
            cm = nm; ct = nt4;
            ca0 = na0; ca1 = na1; ca2 = na2;
            cb0 = nb0; cb1 = nb1; cb2 = nb2;
        }
        idx = nidx;
    }
    __syncthreads();
    for (int i = threadIdx.x; i < 3 * NRBINS; i += THREADS) {
        unsigned long long p = lpk[i];
        if (p) atomicAdd(&gpk[i], p);
    }
    for (int i = threadIdx.x; i < 3 * NBINS; i += THREADS) {
        unsigned h = lht[i];
        if (h) atomicAdd(&ght[i], h);
    }
}

__global__ __launch_bounds__(NBINS) void table_loss(
        const unsigned long long* __restrict__ gpk,
        const unsigned* __restrict__ ght, float* __restrict__ out) {
    __shared__ float cdf[6][NBINS];
    __shared__ float tot[6];
    const int t = threadIdx.x;  // 0..255

    // decode refined bins: r even -> (hb,tb)=(r/2,r/2); r odd -> ((r+1)/2,(r-1)/2)
    unsigned long long pe[3], po[3];
    #pragma unroll
    for (int ch = 0; ch < 3; ++ch) {
        pe[ch] = gpk[ch * NRBINS + 2 * t];
        po[ch] = gpk[ch * NRBINS + 2 * t + 1];
        unsigned long long pp = (t > 0) ? gpk[ch * NRBINS + 2 * t - 1] : 0ULL;
        // src hist bin t: counts from r=2t (even) and r=2t-1 (odd)
        cdf[ch][t] = (float)((pe[ch] >> CNT_SHIFT) + (pp >> CNT_SHIFT));
        cdf[3 + ch][t] = (float)ght[ch * NBINS + t];
    }
    __syncthreads();
    // Hillis-Steele inclusive scan; partials are integers < 2^24 -> exact
    #pragma unroll
    for (int off = 1; off < NBINS; off <<= 1) {
        float add[6];
        #pragma unroll
        for (int j = 0; j < 6; ++j) add[j] = (t >= off) ? cdf[j][t - off] : 0.0f;
        __syncthreads();
        #pragma unroll
        for (int j = 0; j < 6; ++j) cdf[j][t] += add[j];
        __syncthreads();
    }
    if (t < 6) tot[t] = fmaxf(cdf[t][NBINS - 1], 1.0f);
    __syncthreads();
    #pragma unroll
    for (int j = 0; j < 6; ++j) cdf[j][t] = cdf[j][t] / tot[j];
    __syncthreads();

    double lsum = 0.0;
    #pragma unroll
    for (int ch = 0; ch < 3; ++ch) {
        const float d = cdf[ch][t];
        const float* ref = cdf[3 + ch];
        // searchsorted side='left': first idx with ref[idx] >= d
        int lo = 0, hi = NBINS;
        while (lo < hi) {
            int mid = (lo + hi) >> 1;
            if (ref[mid] < d) lo = mid + 1; else hi = mid;
        }
        int cand = min(max(lo, 1), NBINS - 1);
        int T = (ref[cand - 1] <= d && ref[cand] >= d) ? cand : t;
        if (t == 0) T = 0;
        if (t == NBINS - 1) T = NBINS - 1;

        // trunc-bin t stats: r=2t and r=2t+1
        const int b = t;
        const double c =
            (double)((pe[ch] >> CNT_SHIFT) + (po[ch] >> CNT_SHIFT));
        const double F =
            (double)((pe[ch] & FRAC_MASK) + (po[ch] & FRAC_MASK)) *
            (1.0 / 4194304.0);
        // pixels with trunc(v)=b: |v-T| = (b-T)+f if T<=b else (T-b)-f
        lsum += (T <= b) ? (c * (double)(b - T) + F)
                         : (c * (double)(T - b) - F);
    }
    // reduce doubles across 4 waves
    #pragma unroll
    for (int off = 32; off; off >>= 1) lsum += __shfl_down(lsum, off, 64);
    __shared__ double wsum[4];
    if ((t & 63) == 0) wsum[t >> 6] = lsum;
    __syncthreads();
    if (t == 0)
        out[0] = (float)((wsum[0] + wsum[1] + wsum[2] + wsum[3]) /
                         (double)(3 * NPIX));
}

extern "C" void kernel_launch(void* const* d_in, const int* in_sizes, int n_in,
                              void* d_out, int out_size, void* d_ws, size_t ws_size,
                              hipStream_t stream) {
    const float* in  = (const float*)d_in[0];
    const float* tar = (const float*)d_in[1];
    const float* ms  = (const float*)d_in[2];
    const float* mt  = (const float*)d_in[3];
    float* out = (float*)d_out;

    unsigned long long* gpk = (unsigned long long*)d_ws;
    unsigned* ght = (unsigned*)((char*)d_ws + GPK_WORDS * 8);

    hipMemsetAsync(d_ws, 0, WS_ZERO_BYTES, stream);
    fused_hist<<<BLOCKS, THREADS, 0, stream>>>(in, tar, ms, mt, gpk, ght);
    table_loss<<<1, NBINS, 0, stream>>>(gpk, ght, out);
}